// Round 14
// baseline (1812.096 us; speedup 1.0000x reference)
//
#include <hip/hip_runtime.h>
#include <math.h>

// BiometricLSTM: 2-layer LSTM, B=512, T=2048, I=3, H=64, fp32 in/out. Output = final h2 (B,64).
//
// R14: balanced merged waves. R13 (1392 us = 1630 cyc/iter) was gated by barrier
// convergence of 8 UNBALANCED waves: L1 waves (16 MFMA) ran ~2x L0 waves (8 MFMA),
// so half the block idled at the barrier every iter, and 8 waves had to arrive.
// Since wall time = per-block chain time (all 512 seqs already parallel), the fix
// is shortening the chain: every wave now does BOTH layers for its 16 columns
// (8 + 16 = 24 MFMA, all waves identical -> no skew), blocks shrink to 4 waves
// (cheaper barrier), and L0/L1 share the h1[it-1] A-fragments (read once).
//
// 128 blocks x 256 threads (4 waves), 4 seqs/block, 1 wave/SIMD.
//   wave w owns gate-cols [16w,16w+16) of all 4 gate classes, both layers.
//   M=4 seqs replicated 4x in MFMA rows (A row = (l16&3)*HSTR) -> C/D reg r =
//   seq r for every quad; lane(quad,l16) selects reg quad (3 cndmask) and
//   updates (seq=quad, col) fully in-lane. 1 L0 + 1 L1 update per lane.
// Same parity/lag-1 pipeline as R12/R13 (proven): iter it = L0 step it + L1 step
// it-1; h1[t],h2[t] at parity t&1. ONE barrier/iter. HSTR=80 -> 0 conflicts (R13).

typedef _Float16 half8 __attribute__((ext_vector_type(8)));
typedef float    f32x4 __attribute__((ext_vector_type(4)));

constexpr int TT = 2048;
constexpr int HSTR = 80;   // h row stride in halves (160 B)

__device__ __forceinline__ float fast_sigmoid(float x) {
    return 1.0f / (1.0f + __expf(-x));
}
// tanh = 1 - 2/(exp(2x)+1): saturates correctly at +-inf
__device__ __forceinline__ float fast_tanh(float x) {
    return 1.0f - 2.0f / (__expf(2.0f * x) + 1.0f);
}
// select component q (lane's quad) from an f32x4 accumulator
__device__ __forceinline__ float sel4(f32x4 v, int q) {
    float r = v[0];
    r = (q == 1) ? v[1] : r;
    r = (q == 2) ? v[2] : r;
    r = (q == 3) ? v[3] : r;
    return r;
}

__global__ __launch_bounds__(256) void lstm2_fused(
    const float* __restrict__ x,
    const float* __restrict__ Wih0, const float* __restrict__ Whh0,
    const float* __restrict__ bih0, const float* __restrict__ bhh0,
    const float* __restrict__ Wih1, const float* __restrict__ Whh1,
    const float* __restrict__ bih1, const float* __restrict__ bhh1,
    float* __restrict__ out)
{
    __shared__ __align__(16) _Float16 h1a[2][4 * HSTR];   // [parity][seq*HSTR + elem]
    __shared__ __align__(16) _Float16 h2a[2][4 * HSTR];

    const int tid  = threadIdx.x;
    const int lane = tid & 63;
    const int wid  = tid >> 6;
    const int quad = lane >> 4;
    const int l16  = lane & 15;
    const int col  = wid * 16 + l16;     // this lane's gate-elem column (0..63)

    // ---- zero h double-buffers ----
    for (int i = tid; i < 2 * 4 * HSTR; i += 256) {
        ((_Float16*)h1a)[i] = (_Float16)0.0f;
        ((_Float16*)h2a)[i] = (_Float16)0.0f;
    }

    // ---- weights (B-fragments, f16): lane holds W[c*64+col][f*32 + quad*8 .. +8] ----
    half8 w0[4][2];     // L0: Whh0
    half8 w1[4][4];     // L1: [Wih1 | Whh1] over K=128
    float bias0[4], bias1[4], wxa[4], wxb[4], wxc[4];
    #pragma unroll
    for (int c = 0; c < 4; ++c) {
        const int row = c * 64 + col;
        #pragma unroll
        for (int f = 0; f < 2; ++f) {
            const float* p = Whh0 + (size_t)row * 64 + f * 32 + quad * 8;
            half8 h;
            #pragma unroll
            for (int u = 0; u < 8; ++u) h[u] = (_Float16)p[u];
            w0[c][f] = h;
        }
        #pragma unroll
        for (int f = 0; f < 4; ++f) {
            const float* base = (f < 2) ? Wih1 : Whh1;
            const float* p = base + (size_t)row * 64 + (f & 1) * 32 + quad * 8;
            half8 h;
            #pragma unroll
            for (int u = 0; u < 8; ++u) h[u] = (_Float16)p[u];
            w1[c][f] = h;
        }
        bias0[c] = bih0[row] + bhh0[row];
        bias1[c] = bih1[row] + bhh1[row];
        wxa[c] = Wih0[row*3+0]; wxb[c] = Wih0[row*3+1]; wxc[c] = Wih0[row*3+2];
    }

    // ---- x prefetch: this lane updates seq = quad ----
    const float* xq = x + (size_t)(blockIdx.x * 4 + quad) * TT * 3;
    float xn0 = xq[0], xn1 = xq[1], xn2 = xq[2];

    float cst0 = 0.0f;   // c-state L0 (seq=quad, col)
    float cst1 = 0.0f;   // c-state L1 (seq=quad, col)

    __syncthreads();

    // iter it: L0 computes step it (it<TT); L1 computes step it-1 (it>=1).
    // h1[t], h2[t] live at parity t&1. ONE barrier per iteration.
    for (int it = 0; it <= TT; ++it) {
        const int cur  = it & 1;
        const int prev = cur ^ 1;

        // shared A-frags: h1[it-1] (used by L0's Whh0 dot AND L1's Wih1 dot)
        const _Float16* hb1 = h1a[prev] + (l16 & 3) * HSTR + quad * 8;
        half8 a0 = *(const half8*)hb1;
        half8 a1 = *(const half8*)(hb1 + 32);

        if (it < TT) {
            // consume prefetched x[it]; prefetch x[it+1] (clamped)
            const float x0 = xn0, x1 = xn1, x2 = xn2;
            const int nt = (it + 1 < TT) ? it + 1 : TT - 1;
            const float* np = xq + nt * 3;
            xn0 = np[0]; xn1 = np[1]; xn2 = np[2];

            f32x4 acc[4];
            #pragma unroll
            for (int c = 0; c < 4; ++c) {
                f32x4 z = {0.f, 0.f, 0.f, 0.f};
                z = __builtin_amdgcn_mfma_f32_16x16x32_f16(a0, w0[c][0], z, 0, 0, 0);
                z = __builtin_amdgcn_mfma_f32_16x16x32_f16(a1, w0[c][1], z, 0, 0, 0);
                acc[c] = z;
            }
            float pi = sel4(acc[0], quad) + bias0[0] + wxa[0]*x0 + wxb[0]*x1 + wxc[0]*x2;
            float pf = sel4(acc[1], quad) + bias0[1] + wxa[1]*x0 + wxb[1]*x1 + wxc[1]*x2;
            float pg = sel4(acc[2], quad) + bias0[2] + wxa[2]*x0 + wxb[2]*x1 + wxc[2]*x2;
            float po = sel4(acc[3], quad) + bias0[3] + wxa[3]*x0 + wxb[3]*x1 + wxc[3]*x2;
            float iv = fast_sigmoid(pi), fv = fast_sigmoid(pf);
            float gv = fast_tanh(pg),    ov = fast_sigmoid(po);
            cst0 = fmaf(fv, cst0, iv * gv);
            h1a[cur][quad * HSTR + col] = (_Float16)(ov * fast_tanh(cst0));   // h1[it]
        }

        if (it >= 1) {
            // L1 step it-1: K 0..63 = h1[it-1] (a0,a1); K 64..127 = h2[it-2] (parity cur)
            const _Float16* hb2 = h2a[cur] + (l16 & 3) * HSTR + quad * 8;
            half8 a2 = *(const half8*)hb2;
            half8 a3 = *(const half8*)(hb2 + 32);
            f32x4 acc[4];
            #pragma unroll
            for (int c = 0; c < 4; ++c) {
                f32x4 z = {0.f, 0.f, 0.f, 0.f};
                z = __builtin_amdgcn_mfma_f32_16x16x32_f16(a0, w1[c][0], z, 0, 0, 0);
                z = __builtin_amdgcn_mfma_f32_16x16x32_f16(a1, w1[c][1], z, 0, 0, 0);
                z = __builtin_amdgcn_mfma_f32_16x16x32_f16(a2, w1[c][2], z, 0, 0, 0);
                z = __builtin_amdgcn_mfma_f32_16x16x32_f16(a3, w1[c][3], z, 0, 0, 0);
                acc[c] = z;
            }
            float pi = sel4(acc[0], quad) + bias1[0];
            float pf = sel4(acc[1], quad) + bias1[1];
            float pg = sel4(acc[2], quad) + bias1[2];
            float po = sel4(acc[3], quad) + bias1[3];
            float iv = fast_sigmoid(pi), fv = fast_sigmoid(pf);
            float gv = fast_tanh(pg),    ov = fast_sigmoid(po);
            cst1 = fmaf(fv, cst1, iv * gv);
            float hv = ov * fast_tanh(cst1);
            h2a[prev][quad * HSTR + col] = (_Float16)hv;                      // h2[it-1]
            if (it == TT)
                out[(size_t)(blockIdx.x * 4 + quad) * 64 + col] = hv;
        }
        __syncthreads();
    }
}

extern "C" void kernel_launch(void* const* d_in, const int* in_sizes, int n_in,
                              void* d_out, int out_size, void* d_ws, size_t ws_size,
                              hipStream_t stream) {
    const float* x    = (const float*)d_in[0];
    const float* Wih0 = (const float*)d_in[1];
    const float* Whh0 = (const float*)d_in[2];
    const float* bih0 = (const float*)d_in[3];
    const float* bhh0 = (const float*)d_in[4];
    const float* Wih1 = (const float*)d_in[5];
    const float* Whh1 = (const float*)d_in[6];
    const float* bih1 = (const float*)d_in[7];
    const float* bhh1 = (const float*)d_in[8];
    float* out = (float*)d_out;

    // 512 sequences / 4 per block = 128 blocks; 256 threads (4 waves, 1/SIMD).
    lstm2_fused<<<128, 256, 0, stream>>>(x, Wih0, Whh0, bih0, bhh0,
                                         Wih1, Whh1, bih1, bhh1, out);
}